// Round 3
// baseline (449.336 us; speedup 1.0000x reference)
//
#include <hip/hip_runtime.h>

// GAT layer: N=8192, IN_DIM=128, OUT_DIM=64, alpha=0.2
// out = elu( softmax_row( mask(lrelu(s1_i + s2_j), adj) ) @ Wh )
//
// R3: attack latency + access pattern.
//  - adj loads lane-contiguous: per b128 instr, lanes 0-31 cover one full
//    512-B row segment, lanes 32-63 the next row (vs R2's 16 scattered rows).
//  - P round-trips a per-wave LDS buffer to reach MFMA A-frag layout
//    (intra-wave -> NO barriers, lgkmcnt only).
//  - JC=16 j-chunks -> 2048 blocks = 8 blocks/CU = 32 waves/CU (100% occ);
//    launch_bounds(256,8) caps VGPR at 64.
//  - ones-column B-fragment (5th MFMA) produces row sums l exactly
//    consistent with the numerator; removes all lacc VALU + shuffles.

#define N 8192
#define IN_DIM 128
#define OUT_DIM 64
#define ALPHA 0.2f
#define LOG2E 1.44269504088896f
#define JC 16            // j-chunks
#define CW (N / JC)      // 512 cols per chunk
#define TW 128           // cols per wave-tile
#define NT (CW / TW)     // 4 tiles per wave
#define LDP 136          // LDS row stride in halfs (128 + 8: b128-aligned pad)

typedef _Float16 half8 __attribute__((ext_vector_type(8)));
typedef _Float16 half4 __attribute__((ext_vector_type(4)));
typedef float f32x4 __attribute__((ext_vector_type(4)));

// ---------------------------------------------------------------------------
// Kernel 1: Wh = x@W (fp16, transposed [f][i]) ; s1 ; s2 ; s2L = log2e*s2
// ---------------------------------------------------------------------------
__global__ __launch_bounds__(64) void wh_kernel(
    const float* __restrict__ x, const float* __restrict__ W,
    const float* __restrict__ a, _Float16* __restrict__ Wh_t,
    float* __restrict__ s1, float* __restrict__ s2,
    float* __restrict__ s2L) {
  __shared__ float xs[IN_DIM];
  const int i = blockIdx.x;
  const int t = threadIdx.x;  // 0..63 = output feature f

  xs[t]      = x[(size_t)i * IN_DIM + t];
  xs[t + 64] = x[(size_t)i * IN_DIM + 64 + t];
  __syncthreads();

  float wh = 0.f;
#pragma unroll
  for (int d = 0; d < IN_DIM; ++d) wh = fmaf(xs[d], W[d * OUT_DIM + t], wh);

  Wh_t[(size_t)t * N + i] = (_Float16)wh;

  float p1 = wh * a[t];
  float p2 = wh * a[64 + t];
#pragma unroll
  for (int off = 32; off; off >>= 1) {
    p1 += __shfl_down(p1, off);
    p2 += __shfl_down(p2, off);
  }
  if (t == 0) {
    s1[i] = p1;
    s2[i] = p2;
    s2L[i] = p2 * LOG2E;
  }
}

// ---------------------------------------------------------------------------
// Kernel 2: M = lrelu(max(s1)+max(s2)) — global score upper bound.
// ---------------------------------------------------------------------------
__global__ __launch_bounds__(256) void max_kernel(
    const float* __restrict__ s1, const float* __restrict__ s2,
    float* __restrict__ Mout) {
  __shared__ float red[8];
  const int t = threadIdx.x;
  float m1 = -1e30f, m2 = -1e30f;
  for (int idx = t; idx < N; idx += 256) {
    m1 = fmaxf(m1, s1[idx]);
    m2 = fmaxf(m2, s2[idx]);
  }
#pragma unroll
  for (int off = 32; off; off >>= 1) {
    m1 = fmaxf(m1, __shfl_down(m1, off));
    m2 = fmaxf(m2, __shfl_down(m2, off));
  }
  if ((t & 63) == 0) {
    red[t >> 6] = m1;
    red[4 + (t >> 6)] = m2;
  }
  __syncthreads();
  if (t == 0) {
    m1 = fmaxf(fmaxf(red[0], red[1]), fmaxf(red[2], red[3]));
    m2 = fmaxf(fmaxf(red[4], red[5]), fmaxf(red[6], red[7]));
    float e = m1 + m2;
    Mout[0] = e > 0.f ? e : ALPHA * e;
  }
}

// ---------------------------------------------------------------------------
// Kernel 3: adj streamer. grid (N/64, JC); wave w owns rows i0..i0+15,
// j in [c*512, (c+1)*512) as 4 tiles of 128 cols.
// Per tile: 8 contiguous adj loads (2 rows each) -> exp -> fp16 -> LDS;
// then 4 MFMA k-steps (A from LDS, B from L2-resident Wh_t, + ones-col).
// ---------------------------------------------------------------------------
__global__ __launch_bounds__(256, 8) void attn_kernel(
    const int* __restrict__ adj, const _Float16* __restrict__ Wh_t,
    const float* __restrict__ s1, const float* __restrict__ s2L,
    const float* __restrict__ Mptr, float* __restrict__ accp,
    float* __restrict__ lp) {
  __shared__ __align__(16) _Float16 Ps[4 * 16 * LDP];  // per-wave 16xLDP

  const int t = threadIdx.x;
  const int w = t >> 6;
  const int lane = t & 63;
  const int q = lane >> 4;
  const int r16 = lane & 15;
  const int half_ = lane >> 5;  // 0/1: which row of the load pair
  const int l32 = lane & 31;    // position within the 512-B row segment
  const int i0 = blockIdx.x * 64 + w * 16;
  const int c = blockIdx.y;
  const int jb = c * CW;

  const float ML = Mptr[0] * LOG2E;

  // per-lane row constants for the load phase (row = 2*it + half_)
  float s1L[8];
#pragma unroll
  for (int it = 0; it < 8; ++it)
    s1L[it] = s1[i0 + 2 * it + half_] * LOG2E;

  // ones-column B fragment: B[k][0] = 1 -> acc4 accumulates row sums of P
  half8 bones;
#pragma unroll
  for (int e = 0; e < 8; ++e) bones[e] = (r16 == 0) ? (_Float16)1.0f : (_Float16)0.0f;

  f32x4 acc[5] = {{0.f, 0.f, 0.f, 0.f}, {0.f, 0.f, 0.f, 0.f},
                  {0.f, 0.f, 0.f, 0.f}, {0.f, 0.f, 0.f, 0.f},
                  {0.f, 0.f, 0.f, 0.f}};

  _Float16* Pw = Ps + w * 16 * LDP;
  const _Float16* ldA = Pw + r16 * LDP + q * 8;  // A-frag read base
  _Float16* stP = Pw + half_ * LDP + l32 * 4;    // write base (row 2it+half_)

  for (int jt = 0; jt < NT; ++jt) {
    const int j0 = jb + jt * TW;

    const float4 sv = *(const float4*)(s2L + j0 + l32 * 4);
    const int* ap = adj + (size_t)(i0 + half_) * N + j0 + l32 * 4;

    // ---- produce the 16x128 P tile (8 loads, each 2 contiguous rows)
#pragma unroll
    for (int it = 0; it < 8; ++it) {
      const int4 av = *(const int4*)(ap + (size_t)it * (2 * N));
      const float s1v = s1L[it];
      float p0, p1, p2, p3, tt, uu;
      tt = s1v + sv.x; uu = fmaxf(tt, ALPHA * tt); p0 = exp2f(uu - ML);
      tt = s1v + sv.y; uu = fmaxf(tt, ALPHA * tt); p1 = exp2f(uu - ML);
      tt = s1v + sv.z; uu = fmaxf(tt, ALPHA * tt); p2 = exp2f(uu - ML);
      tt = s1v + sv.w; uu = fmaxf(tt, ALPHA * tt); p3 = exp2f(uu - ML);
      half4 hv;
      hv[0] = (_Float16)(av.x != 0 ? p0 : 0.f);
      hv[1] = (_Float16)(av.y != 0 ? p1 : 0.f);
      hv[2] = (_Float16)(av.z != 0 ? p2 : 0.f);
      hv[3] = (_Float16)(av.w != 0 ? p3 : 0.f);
      *(half4*)(stP + it * (2 * LDP)) = hv;
    }

    // ---- MFMA: 4 k-steps of 32, A from LDS, B from Wh_t, + ones column
#pragma unroll
    for (int ks = 0; ks < 4; ++ks) {
      const half8 aF = *(const half8*)(ldA + ks * 32);
      const int kcol = j0 + ks * 32 + q * 8;
#pragma unroll
      for (int fg = 0; fg < 4; ++fg) {
        const half8 bf =
            *(const half8*)(Wh_t + (size_t)(fg * 16 + r16) * N + kcol);
        acc[fg] =
            __builtin_amdgcn_mfma_f32_16x16x32_f16(aF, bf, acc[fg], 0, 0, 0);
      }
      acc[4] =
          __builtin_amdgcn_mfma_f32_16x16x32_f16(aF, bones, acc[4], 0, 0, 0);
    }
  }

  // ---- store partials. C/D: row = q*4+r, col = r16 (per fg block).
#pragma unroll
  for (int fg = 0; fg < 4; ++fg) {
#pragma unroll
    for (int r = 0; r < 4; ++r) {
      accp[((size_t)c * N + i0 + q * 4 + r) * OUT_DIM + fg * 16 + r16] =
          acc[fg][r];
    }
  }
  if (r16 == 0) {
#pragma unroll
    for (int r = 0; r < 4; ++r) lp[(size_t)c * N + i0 + q * 4 + r] = acc[4][r];
  }
}

// ---------------------------------------------------------------------------
// Kernel 4: combine JC partials, normalize, ELU.
// ---------------------------------------------------------------------------
__global__ __launch_bounds__(256) void reduce_kernel(
    const float* __restrict__ accp, const float* __restrict__ lp,
    float* __restrict__ out) {
  const int tid = blockIdx.x * 256 + threadIdx.x;  // over N*OUT_DIM
  const int i = tid >> 6;                          // row
  float s = 0.f, l = 0.f;
#pragma unroll
  for (int c = 0; c < JC; ++c) s += accp[(size_t)c * N * OUT_DIM + tid];
#pragma unroll
  for (int c = 0; c < JC; ++c) l += lp[(size_t)c * N + i];
  float v = s / l;
  out[tid] = v > 0.f ? v : expm1f(v);
}

// ---------------------------------------------------------------------------
extern "C" void kernel_launch(void* const* d_in, const int* in_sizes, int n_in,
                              void* d_out, int out_size, void* d_ws,
                              size_t ws_size, hipStream_t stream) {
  const float* x = (const float*)d_in[0];
  const int* adj = (const int*)d_in[1];
  const float* W = (const float*)d_in[2];
  const float* a = (const float*)d_in[3];
  float* out = (float*)d_out;

  char* ws = (char*)d_ws;
  _Float16* Wh_t = (_Float16*)ws;                  // 1 MiB
  float* s1 = (float*)(ws + (1u << 20));           // 32 KiB
  float* s2 = s1 + N;                              // 32 KiB
  float* s2L = s2 + N;                             // 32 KiB
  float* M = s2L + N;                              // 4 B
  float* accp = (float*)(ws + (2u << 20));         // JC*N*64*4 = 32 MiB
  float* lp = accp + (size_t)JC * N * OUT_DIM;     // 512 KiB

  wh_kernel<<<N, 64, 0, stream>>>(x, W, a, Wh_t, s1, s2, s2L);
  max_kernel<<<1, 256, 0, stream>>>(s1, s2, M);
  attn_kernel<<<dim3(N / 64, JC), 256, 0, stream>>>(adj, Wh_t, s1, s2L, M,
                                                    accp, lp);
  reduce_kernel<<<N * OUT_DIM / 256, 256, 0, stream>>>(accp, lp, out);
}